// Round 1
// baseline (1565.454 us; speedup 1.0000x reference)
//
#include <hip/hip_runtime.h>
#include <stdint.h>
#include <stddef.h>

// Problem constants (from reference setup_inputs)
#define NSLOT 8
#define OUTF  4096
#define INF   4096
#define MDIM  16384   // B*S = 8*2048
#define KDIM  4096
#define NDIM  4096

typedef __bf16 bf16x8 __attribute__((ext_vector_type(8)));
typedef float f32x4 __attribute__((ext_vector_type(4)));
typedef unsigned short u16x8 __attribute__((ext_vector_type(8)));

// round-to-nearest-even f32 -> bf16 bits (finite inputs only)
__device__ __forceinline__ unsigned short f2bf(float f) {
  unsigned u = __builtin_bit_cast(unsigned, f);
  u += 0x7fffu + ((u >> 16) & 1u);
  return (unsigned short)(u >> 16);
}

// ---- kernel 1: scalar coefficients ----
// co[0..7] = scale*wscale, co[8] = scale.wzp, co[9..16] = scale*bscale, co[17] = scale.bzp
__global__ void coeff_kernel(const float* __restrict__ scale,
                             const float* __restrict__ wscale,
                             const int* __restrict__ wzp,
                             const float* __restrict__ bscale,
                             const int* __restrict__ bzp,
                             float* __restrict__ co) {
  if (threadIdx.x == 0) {
    float c = 0.f, cb = 0.f;
    for (int i = 0; i < NSLOT; ++i) {
      co[i]     = scale[i] * wscale[i];
      co[9 + i] = scale[i] * bscale[i];
      c  += scale[i] * (float)wzp[i];
      cb += scale[i] * (float)bzp[i];
    }
    co[8]  = c;
    co[17] = cb;
  }
}

// ---- kernel 2: W' = weight + sum_i a_i*wq_i + c, stored as bf16 bits ----
// 8 elements per thread; 16 B stores.
__global__ __launch_bounds__(256) void dequant_w(const float* __restrict__ weight,
                                                 const int* __restrict__ wq,
                                                 const float* __restrict__ co,
                                                 unsigned short* __restrict__ wd) {
  const size_t base = ((size_t)blockIdx.x * 256 + threadIdx.x) * 8;
  const float c = co[8];
  float4 w0 = *(const float4*)(weight + base);
  float4 w1 = *(const float4*)(weight + base + 4);
  float acc[8] = {w0.x + c, w0.y + c, w0.z + c, w0.w + c,
                  w1.x + c, w1.y + c, w1.z + c, w1.w + c};
#pragma unroll
  for (int i = 0; i < NSLOT; ++i) {
    const float a = co[i];
    const int* q = wq + (size_t)i * ((size_t)OUTF * INF) + base;
    int4 q0 = *(const int4*)q;
    int4 q1 = *(const int4*)(q + 4);
    acc[0] += a * (float)q0.x; acc[1] += a * (float)q0.y;
    acc[2] += a * (float)q0.z; acc[3] += a * (float)q0.w;
    acc[4] += a * (float)q1.x; acc[5] += a * (float)q1.y;
    acc[6] += a * (float)q1.z; acc[7] += a * (float)q1.w;
  }
  u16x8 p;
#pragma unroll
  for (int e = 0; e < 8; ++e) p[e] = f2bf(acc[e]);
  *(u16x8*)(wd + base) = p;
}

// ---- kernel 3: x f32 -> bf16 ----
__global__ __launch_bounds__(256) void xconv(const float* __restrict__ x,
                                             unsigned short* __restrict__ xb) {
  const size_t base = ((size_t)blockIdx.x * 256 + threadIdx.x) * 8;
  float4 v0 = *(const float4*)(x + base);
  float4 v1 = *(const float4*)(x + base + 4);
  u16x8 p;
  p[0] = f2bf(v0.x); p[1] = f2bf(v0.y); p[2] = f2bf(v0.z); p[3] = f2bf(v0.w);
  p[4] = f2bf(v1.x); p[5] = f2bf(v1.y); p[6] = f2bf(v1.z); p[7] = f2bf(v1.w);
  *(u16x8*)(xb + base) = p;
}

// ---- kernel 4: b' = bias + sum_i ab_i*bq_i + cb ----
__global__ __launch_bounds__(256) void bias_fuse(const float* __restrict__ bias,
                                                 const int* __restrict__ bq,
                                                 const float* __restrict__ co,
                                                 float* __restrict__ bv) {
  const int o = blockIdx.x * 256 + threadIdx.x;
  float acc = bias[o] + co[17];
#pragma unroll
  for (int i = 0; i < NSLOT; ++i)
    acc += co[9 + i] * (float)bq[i * OUTF + o];
  bv[o] = acc;
}

// ---- kernel 5: bf16 GEMM, C = A(16384x4096) * W'(4096x4096)^T + b' ----
// m97 structure: 128x128 tile, BK=32, 4 waves 2x2 (64x64 each),
// 4x4 mfma_f32_16x16x32_bf16 accumulators, global_load_lds width=16 staging.
__global__ __launch_bounds__(256, 2) void gemm_bt(const unsigned short* __restrict__ A,
                                                  const unsigned short* __restrict__ Bw,
                                                  const float* __restrict__ bv,
                                                  float* __restrict__ C) {
  __shared__ __align__(16) unsigned short sA[128 * 32];
  __shared__ __align__(16) unsigned short sB[128 * 32];

  const int t    = threadIdx.x;
  const int lane = t & 63;
  const int wave = t >> 6;
  const int wm = (wave >> 1) * 64;  // wave tile row offset within block tile
  const int wn = (wave & 1) * 64;   // wave tile col offset

  const int m0 = blockIdx.y * 128;
  const int n0 = blockIdx.x * 128;

  // staging: thread t loads 8 bf16 (16 B): row = t/4 (+64), col = (t%4)*8
  const int srow = t >> 2;
  const int scol = (t & 3) * 8;
  const size_t a_off = (size_t)(m0 + srow) * KDIM + scol;
  const size_t b_off = (size_t)(n0 + srow) * KDIM + scol;

  f32x4 acc[4][4] = {};

  const int qa = (lane >> 4) * 8;   // k-offset of this lane's fragment
  const int fr = lane & 15;         // row (A) / col (B) within 16

  for (int k0 = 0; k0 < KDIM; k0 += 32) {
    __syncthreads();
    {
      const unsigned short* ga = A + a_off + k0;
      const unsigned short* gb = Bw + b_off + k0;
      __builtin_amdgcn_global_load_lds(
          (const __attribute__((address_space(1))) void*)ga,
          (__attribute__((address_space(3))) void*)(sA + t * 8), 16, 0, 0);
      __builtin_amdgcn_global_load_lds(
          (const __attribute__((address_space(1))) void*)(ga + (size_t)64 * KDIM),
          (__attribute__((address_space(3))) void*)(sA + 2048 + t * 8), 16, 0, 0);
      __builtin_amdgcn_global_load_lds(
          (const __attribute__((address_space(1))) void*)gb,
          (__attribute__((address_space(3))) void*)(sB + t * 8), 16, 0, 0);
      __builtin_amdgcn_global_load_lds(
          (const __attribute__((address_space(1))) void*)(gb + (size_t)64 * KDIM),
          (__attribute__((address_space(3))) void*)(sB + 2048 + t * 8), 16, 0, 0);
    }
    __syncthreads();

    bf16x8 af[4], bf[4];
#pragma unroll
    for (int i = 0; i < 4; ++i)
      af[i] = *(const bf16x8*)(sA + (wm + i * 16 + fr) * 32 + qa);
#pragma unroll
    for (int j = 0; j < 4; ++j)
      bf[j] = *(const bf16x8*)(sB + (wn + j * 16 + fr) * 32 + qa);

#pragma unroll
    for (int i = 0; i < 4; ++i)
#pragma unroll
      for (int j = 0; j < 4; ++j)
        acc[i][j] = __builtin_amdgcn_mfma_f32_16x16x32_bf16(af[i], bf[j], acc[i][j], 0, 0, 0);
  }

  // epilogue: C/D layout col = lane&15, row = (lane>>4)*4 + reg
  const int row0 = m0 + wm + (lane >> 4) * 4;
  const int col0 = n0 + wn + (lane & 15);
#pragma unroll
  for (int j = 0; j < 4; ++j) {
    const int col = col0 + j * 16;
    const float bb = bv[col];
#pragma unroll
    for (int i = 0; i < 4; ++i) {
      const int row = row0 + i * 16;
#pragma unroll
      for (int r = 0; r < 4; ++r)
        C[(size_t)(row + r) * NDIM + col] = acc[i][j][r] + bb;
    }
  }
}

extern "C" void kernel_launch(void* const* d_in, const int* in_sizes, int n_in,
                              void* d_out, int out_size, void* d_ws, size_t ws_size,
                              hipStream_t stream) {
  const float* x      = (const float*)d_in[0];
  const float* weight = (const float*)d_in[1];
  const float* bias   = (const float*)d_in[2];
  const float* scale  = (const float*)d_in[3];
  const int*   wq     = (const int*)d_in[4];
  const float* wscale = (const float*)d_in[5];
  const int*   wzp    = (const int*)d_in[6];
  const int*   bq     = (const int*)d_in[7];
  const float* bscale = (const float*)d_in[8];
  const int*   bzp    = (const int*)d_in[9];
  float* out = (float*)d_out;

  // workspace layout
  char* ws = (char*)d_ws;
  unsigned short* wd = (unsigned short*)(ws);                              // 32 MB  bf16 W'
  unsigned short* xb = (unsigned short*)(ws + 33554432);                   // 128 MB bf16 x
  float* bv = (float*)(ws + 33554432 + 134217728);                         // 16 KB  b'
  float* co = (float*)(ws + 33554432 + 134217728 + 16384);                 // coeffs

  coeff_kernel<<<1, 64, 0, stream>>>(scale, wscale, wzp, bscale, bzp, co);
  dequant_w<<<(OUTF * (size_t)INF) / 8 / 256, 256, 0, stream>>>(weight, wq, co, wd);
  xconv<<<((size_t)MDIM * KDIM) / 8 / 256, 256, 0, stream>>>(x, xb);
  bias_fuse<<<OUTF / 256, 256, 0, stream>>>(bias, bq, co, bv);
  gemm_bt<<<dim3(NDIM / 128, MDIM / 128), 256, 0, stream>>>(xb, wd, bv, out);
}